// Round 19
// baseline (482.334 us; speedup 1.0000x reference)
//
#include <hip/hip_runtime.h>
#include <hip/hip_bf16.h>
#include <math.h>
#include <string.h>

#define IH 48
#define IW 48
#define LTOT 2304      // 48*48
#define CS 128
#define HS 96
#define KRED 1152      // 3*3*128
#define CRED 2048      // 4*4*128

typedef unsigned short u16;
typedef __attribute__((ext_vector_type(8))) short short8;
typedef __attribute__((ext_vector_type(8))) unsigned short ushort8;
typedef __attribute__((ext_vector_type(4))) float floatx4;

#define NS    ((size_t)LTOT*LTOT)     // 5,308,416
#define PLANE ((size_t)LTOT*KRED)     // 2,654,208

// ---- region layout (bytes), per batch slice (~52MB; 4x fits ws) ----
#define OFF_APL  ((size_t)0)           // 2 bf16 W planes
#define OFF_BPL  ((size_t)10616832)    // 2 bf16 Xp planes
#define OFF_S    ((size_t)21233664)    // NS fp32 raw scores
#define OFF_C    ((size_t)42467328)    // C rows bf16: 2304*2048*2 B
#define OFF_SM   ((size_t)51904512)    // mmv(2304 f32)
#define REGION   ((size_t)51922944)

__device__ __forceinline__ u16 f2bf(float v) {
    __hip_bfloat16 h = __float2bfloat16(v);
    return *reinterpret_cast<u16*>(&h);
}
__device__ __forceinline__ float bf2f(u16 b) {
    __hip_bfloat16 h = *reinterpret_cast<__hip_bfloat16*>(&b);
    return __bfloat162float(h);
}
__device__ __forceinline__ void split2(float v, u16& a, u16& b) {
    a = f2bf(v);
    b = f2bf(v - bf2f(a));
}
__device__ __forceinline__ floatx4 L4(const float* p) {
    floatx4 r;
    __builtin_memcpy(&r, p, 16);   // align-4 vector load (HW supports unaligned dwordx4)
    return r;
}

// ---------------- fused W norm + gather + split (register-resident row) ----------------
__global__ __launch_bounds__(256) void k_wgather(const float* __restrict__ b,
                                                 u16* __restrict__ Ag,
                                                 int b0, size_t zsU) {
    int bi = b0 + blockIdx.z;
    u16* A = Ag + (size_t)blockIdx.z * zsU;
    int l = blockIdx.x, t = threadIdx.x;
    __shared__ float red[256];
    float myv[5];
    float ss = 0.f;
#pragma unroll
    for (int k = 0; k < 5; ++k) {
        int G = t + 256 * k;
        float val = 0.f;
        if (G < KRED) {
            int F = l * KRED + G;
            int p2 = F / LTOT, s = F - p2 * LTOT;
            int i = p2 / 384, j = (p2 / 128) % 3, c = p2 & 127;
            int u = s / IW + i - 1, v = s % IW + j - 1;
            if (u >= 0 && u < IH && v >= 0 && v < IW)
                val = b[(((size_t)bi * CS + c) * HS + 2 * u) * HS + 2 * v];
        }
        myv[k] = val;
        ss += val * val;
    }
    red[t] = ss; __syncthreads();
    for (int o = 128; o > 0; o >>= 1) { if (t < o) red[t] += red[t + o]; __syncthreads(); }
    float ninv = 1.0f / fmaxf(sqrtf(red[0] + 1e-8f), 1e-4f);
#pragma unroll
    for (int k = 0; k < 5; ++k) {
        int G = t + 256 * k;
        if (G < KRED) {
            u16 h1, h2; split2(myv[k] * ninv, h1, h2);
            size_t F = (size_t)l * KRED + G;
            A[F] = h1; A[PLANE + F] = h2;
        }
    }
}

// ---------------- gather Xp (split) — LDS-tiled ----------------
__global__ __launch_bounds__(256) void k_gather_x_tiled(const float* __restrict__ f,
                                                        u16* __restrict__ Bg,
                                                        int b0, size_t zsU) {
    __shared__ float ldsf[128 * 55];   // [c][3][18] padded 54->55
    int bi = b0 + blockIdx.z;
    u16* B = Bg + (size_t)blockIdx.z * zsU;
    int bx = blockIdx.x;
    int y = bx / 3, x0 = (bx % 3) * 16;
    int t = threadIdx.x;
    for (int i = 0; i < 27; ++i) {
        int g = i * 256 + t;
        if (g < 6912) {
            int vl = g % 18;
            int row = (g / 18) % 3;
            int c = g / 54;
            int u = y + row - 1;
            int v = x0 - 1 + vl;
            float val = 0.f;
            if (u >= 0 && u < IH && v >= 0 && v < IW)
                val = f[(((size_t)bi * CS + c) * HS + 2 * u) * HS + 2 * v];
            ldsf[c * 55 + row * 18 + vl] = val;
        }
    }
    __syncthreads();
    for (int i = 0; i < 72; ++i) {
        int o = i * 256 + t;
        int xp = o / 1152, G = o - xp * 1152;
        int k1 = G / 384, k2 = (G >> 7) % 3, c = G & 127;
        float val = ldsf[c * 55 + k1 * 18 + xp + k2];
        u16 h1, h2; split2(val, h1, h2);
        size_t idx = (size_t)(y * IW + x0 + xp) * KRED + G;
        B[idx] = h1; B[PLANE + idx] = h2;
    }
}

// ---------------- mask vector ----------------
__global__ __launch_bounds__(256) void k_mm(const float* __restrict__ mask,
                                            float* __restrict__ mmvg, int b0, size_t zsF) {
    int bi = b0 + blockIdx.z;
    float* out = mmvg + (size_t)blockIdx.z * zsF;
    int q = blockIdx.x * 256 + threadIdx.x;
    if (q >= LTOT) return;
    float ssum = 0.f;
    for (int t = 0; t < 9; t++) {
        int F = q * 9 + t;
        int pm = F / LTOT, s = F % LTOT;
        int i = pm / 3, j = pm % 3;
        int u = s / IW + i - 1, v = s % IW + j - 1;
        float val = 0.f;
        if (u >= 0 && u < IH && v >= 0 && v < IW)
            val = mask[((size_t)bi * HS + 2 * u) * HS + 2 * v];
        ssum += 1.0f - val;
    }
    out[q] = (ssum / 9.0f < 0.85f) ? 1.0f : 0.0f;
}

// ---------------- MFMA GEMM (NT) — unchanged proven structure ----------------
template <int NP, int BK>
__global__ __launch_bounds__(256) void k_gemm_mfma(const u16* __restrict__ Ag,
                                                   const u16* __restrict__ Bg,
                                                   float* __restrict__ Cg,
                                                   size_t zsA, size_t zsB, size_t zsC,
                                                   size_t planeStride,
                                                   int M, int N, int K) {
    constexpr int SLOTS = BK / 8;
    constexpr int SMASK = SLOTS - 1;
    constexpr int TSZ = 128 * BK;
    constexpr int NLD = NP * BK / 16;
    __shared__ u16 lds[2 * NP * TSZ];
    u16* As = lds;
    u16* Bs = lds + NP * TSZ;
    const int tid = threadIdx.x;
    const int lane = tid & 63;
    const int wave = tid >> 6;
    const int wr = (wave >> 1) * 64, wc = (wave & 1) * 64;
    const int lrow = lane & 15, lq = lane >> 4;

    unsigned gx = gridDim.x, gy = gridDim.y;
    unsigned nwg = gx * gy * gridDim.z;
    unsigned wg = (blockIdx.z * gy + blockIdx.y) * gx + blockIdx.x;
    {
        unsigned q = nwg >> 3, r = nwg & 7, xcd = wg & 7, lid = wg >> 3;
        wg = (xcd < r ? xcd * (q + 1) : r * (q + 1) + (xcd - r) * q) + lid;
    }
    unsigned z = wg / (gx * gy);
    unsigned rem2 = wg - z * gx * gy;
    const int bm = (int)(rem2 / gx) * 128, bn = (int)(rem2 % gx) * 128;

    const u16* A = Ag + (size_t)z * zsA;
    const u16* B = Bg + (size_t)z * zsB;
    float* C = Cg + (size_t)z * zsC;

    floatx4 acc[4][4];
#pragma unroll
    for (int i = 0; i < 4; i++)
#pragma unroll
        for (int j = 0; j < 4; j++) acc[i][j] = (floatx4){0.f, 0.f, 0.f, 0.f};

    for (int kt = 0; kt < K; kt += BK) {
        ushort8 stA[NLD], stB[NLD];
#pragma unroll
        for (int e = 0; e < NLD; ++e) {
            int g = e * 256 + tid;
            int p = g / (128 * SLOTS);
            int gg = g % (128 * SLOTS);
            int row = gg / SLOTS, slot = gg & SMASK;
            stA[e] = *(const ushort8*)(A + (size_t)p * planeStride + (size_t)(bm + row) * K + kt + slot * 8);
            stB[e] = *(const ushort8*)(B + (size_t)p * planeStride + (size_t)(bn + row) * K + kt + slot * 8);
        }
        __syncthreads();
#pragma unroll
        for (int e = 0; e < NLD; ++e) {
            int g = e * 256 + tid;
            int p = g / (128 * SLOTS);
            int gg = g % (128 * SLOTS);
            int row = gg / SLOTS, slot = gg & SMASK;
            int dst = p * TSZ + row * BK + ((slot ^ (row & SMASK)) << 3);
            *(ushort8*)&As[dst] = stA[e];
            *(ushort8*)&Bs[dst] = stB[e];
        }
        __syncthreads();

#pragma unroll
        for (int ks = 0; ks < BK / 32; ++ks) {
            short8 af[NP][4];
#pragma unroll
            for (int p = 0; p < NP; ++p)
#pragma unroll
                for (int mi = 0; mi < 4; ++mi) {
                    int row = wr + mi * 16 + lrow;
                    af[p][mi] = *(const short8*)&As[p * TSZ + row * BK + ((((ks << 2) | lq) ^ (row & SMASK)) << 3)];
                }
#pragma unroll
            for (int ni = 0; ni < 4; ++ni) {
                short8 bfr[NP];
                int rowb = wc + ni * 16 + lrow;
                int bslot = ((((ks << 2) | lq) ^ (rowb & SMASK)) << 3);
#pragma unroll
                for (int p = 0; p < NP; ++p)
                    bfr[p] = *(const short8*)&Bs[p * TSZ + rowb * BK + bslot];
#pragma unroll
                for (int mi = 0; mi < 4; ++mi) {
                    if constexpr (NP == 1) {
                        acc[mi][ni] = __builtin_amdgcn_mfma_f32_16x16x32_bf16(af[0][mi], bfr[0], acc[mi][ni], 0, 0, 0);
                    } else {
                        acc[mi][ni] = __builtin_amdgcn_mfma_f32_16x16x32_bf16(af[1][mi], bfr[0], acc[mi][ni], 0, 0, 0);
                        acc[mi][ni] = __builtin_amdgcn_mfma_f32_16x16x32_bf16(af[0][mi], bfr[1], acc[mi][ni], 0, 0, 0);
                        acc[mi][ni] = __builtin_amdgcn_mfma_f32_16x16x32_bf16(af[0][mi], bfr[0], acc[mi][ni], 0, 0, 0);
                    }
                }
            }
        }
    }

    const int r0 = bm + wr + (lane >> 4) * 4;
    const int c0 = bn + wc + (lane & 15);
#pragma unroll
    for (int mi = 0; mi < 4; ++mi)
#pragma unroll
        for (int ni = 0; ni < 4; ++ni)
#pragma unroll
            for (int j = 0; j < 4; ++j)
                C[(size_t)(r0 + mi * 16 + j) * N + (c0 + ni * 16)] = acc[mi][ni][j];
}

// ---------------- fused stencil+softmax+argmax + sparse context gather ----------------
// Round-18 semantics; stencil vectorized: each of the 9 taps is one row at one
// wave-uniform column offset, so 4 consecutive outputs = 9 unaligned float4 loads.
// Interior chunks (q in [13,563)) take the fast path (same tap-add order =>
// bit-identical); border chunks keep the scalar guarded code verbatim.
__device__ __forceinline__ int permi(int a) { return (a % 48) * 48 + a / 48; }

__global__ __launch_bounds__(256) void k_fusesoftmax(const float* __restrict__ Sg,
                                                     const float* __restrict__ mmg,
                                                     const float* __restrict__ bsrc,
                                                     u16* __restrict__ Cg,
                                                     float* __restrict__ offout,
                                                     int b0, size_t zsF, size_t zsU) {
    // flat bijective XCD swizzle over (z,l): contiguous one-z l-chunk per XCD
    unsigned nwg = gridDim.x;
    unsigned wg0 = blockIdx.x;
    unsigned qq = nwg >> 3, rr = nwg & 7, xcd = wg0 & 7, lid = wg0 >> 3;
    unsigned wg = (xcd < rr ? xcd * (qq + 1) : rr * (qq + 1) + (xcd - rr) * qq) + lid;
    int z = wg / LTOT;
    int l = wg - z * LTOT;
    int bi = b0 + z;
    const float* S = Sg + (size_t)z * zsF;
    const float* mm = mmg + (size_t)z * zsF;
    u16* C = Cg + (size_t)z * zsU;
    int t = threadIdx.x;
    __shared__ float redv[256];
    __shared__ int redi[256];
    __shared__ int scand[2304];
    __shared__ float scv[2304];
    __shared__ int scnt;
    __shared__ int sAny;
    if (t == 0) { scnt = 0; sAny = 0; }

    const bool hasRm = (l >= 1);
    const bool hasRp = (l <= 2302);
    const int rm = hasRm ? ((l >= 48) ? l - 48 : 2255 + l) : 0;
    const int rp = hasRp ? ((l < 2256) ? l + 48 : l - 2255) : 0;
    const float* pr_l  = S + (size_t)l * LTOT;
    const float* pr_lm = S + (size_t)(l >= 1 ? l - 1 : 0) * LTOT;
    const float* pr_lp = S + (size_t)(l < 2303 ? l + 1 : l) * LTOT;
    const float* pr_m  = S + (size_t)rm * LTOT;
    const float* pr_mm = S + (size_t)(rm >= 1 ? rm - 1 : 0) * LTOT;
    const float* pr_mp = S + (size_t)(rm < 2303 ? rm + 1 : rm) * LTOT;
    const float* pr_p  = S + (size_t)rp * LTOT;
    const float* pr_pm = S + (size_t)(rp >= 1 ? rp - 1 : 0) * LTOT;
    const float* pr_pp = S + (size_t)(rp < 2303 ? rp + 1 : rp) * LTOT;
    const bool gLm = (l >= 1), gLp = (l < 2303);
    const bool gMm = (rm >= 1), gMp = (rm < 2303);
    const bool gPm = (rp >= 1), gPp = (rp < 2303);

    // elements: float4 chunks q = t, t+256, t+512(<576 i.e. t<64)
    const int nch = (t < 64) ? 3 : 2;
    float v[12];
    bool mk[12];
    int nMaskLoc = 0;
    for (int ch = 0; ch < nch; ++ch) {
        int q = t + 256 * ch;
        int p0 = q * 4;
        floatx4 d;
        if (q >= 13 && q < 563) {
            d = L4(pr_l + p0);
            if (gLm) d += L4(pr_lm + p0 - 1);
            if (gLp) d += L4(pr_lp + p0 + 1);
            if (hasRm) {
                d += L4(pr_m + p0 - 48);
                if (gMm) d += L4(pr_mm + p0 - 49);
                if (gMp) d += L4(pr_mp + p0 - 47);
            }
            if (hasRp) {
                d += L4(pr_p + p0 + 48);
                if (gPm) d += L4(pr_pm + p0 + 47);
                if (gPp) d += L4(pr_pp + p0 + 49);
            }
        } else {
#pragma unroll
            for (int e = 0; e < 4; ++e) {
                int p = p0 + e;
                const bool cm = (p >= 1), cp = (p < 2303);
                int pm = (p >= 48) ? p - 48 : 2255 + p;
                int pp = (p < 2256) ? p + 48 : p - 2255;
                float dd = pr_l[p];
                { float x = pr_lm[cm ? p - 1 : 0];            dd += (gLm && cm) ? x : 0.f; }
                { float x = pr_lp[cp ? p + 1 : p];            dd += (gLp && cp) ? x : 0.f; }
                { float x = pr_m[pm];                         dd += (hasRm && cm) ? x : 0.f; }
                { bool g = hasRm && cm && gMm && (pm >= 1);
                  float x = pr_mm[(pm >= 1) ? pm - 1 : 0];    dd += g ? x : 0.f; }
                { bool g = hasRm && cm && gMp && (pm < 2303);
                  float x = pr_mp[(pm < 2303) ? pm + 1 : pm]; dd += g ? x : 0.f; }
                { float x = pr_p[pp];                         dd += (hasRp && cp) ? x : 0.f; }
                { bool g = hasRp && cp && gPm && (pp >= 1);
                  float x = pr_pm[(pp >= 1) ? pp - 1 : 0];    dd += g ? x : 0.f; }
                { bool g = hasRp && cp && gPp && (pp < 2303);
                  float x = pr_pp[(pp < 2303) ? pp + 1 : pp]; dd += g ? x : 0.f; }
                d[e] = dd;
            }
        }
        floatx4 m4 = *(const floatx4*)(mm + p0);   // 16B-aligned
#pragma unroll
        for (int e = 0; e < 4; ++e) {
            int idx = ch * 4 + e;
            mk[idx] = (m4[e] > 0.f);
            if (!mk[idx]) nMaskLoc++;
            v[idx] = d[e] * m4[e] * 10.0f;
        }
    }
    // joint reduction: unmasked max + first index (elements ascend in p per thread)
    float lmu = -1e30f; int lidx = 0x7fffffff;
    for (int ch = 0; ch < nch; ++ch) {
#pragma unroll
        for (int e = 0; e < 4; ++e) {
            int idx = ch * 4 + e;
            int p = (t + 256 * ch) * 4 + e;
            if (mk[idx] && v[idx] > lmu) { lmu = v[idx]; lidx = p; }
        }
    }
    if (nMaskLoc) sAny = 1;   // benign race
    redv[t] = lmu; redi[t] = lidx; __syncthreads();
    for (int o = 128; o > 0; o >>= 1) {
        if (t < o) {
            if (redv[t + o] > redv[t] || (redv[t + o] == redv[t] && redi[t + o] < redi[t])) {
                redv[t] = redv[t + o]; redi[t] = redi[t + o];
            }
        }
        __syncthreads();
    }
    float mu = redv[0];
    int muIdx = redi[0];
    int anyM = sAny;
    __syncthreads();
    redi[t] = nMaskLoc; __syncthreads();
    for (int o = 128; o > 0; o >>= 1) { if (t < o) redi[t] += redi[t + o]; __syncthreads(); }
    int nMask = redi[0];
    __syncthreads();

    float mx = anyM ? fmaxf(mu, 0.f) : mu;

    // candidates within 20 logits of unmasked max (full list, exact Z)
    for (int ch = 0; ch < nch; ++ch) {
#pragma unroll
        for (int e = 0; e < 4; ++e) {
            int idx = ch * 4 + e;
            int p = (t + 256 * ch) * 4 + e;
            if (mk[idx] && v[idx] >= mu - 20.0f) {
                int pos = atomicAdd(&scnt, 1);
                scand[pos] = p;
                scv[pos] = v[idx];
            }
        }
    }
    __syncthreads();
    int cnt = scnt;

    float Z = (float)nMask * __expf(0.f - mx);
    for (int ci = 0; ci < cnt; ++ci) Z += __expf(scv[ci] - mx);

    if (t == 0) {
        int bestp = (cnt > 0) ? muIdx : 0;
        int ly = l / IW, lx = l % IW;
        offout[((size_t)bi * 2 + 0) * LTOT + l] = (float)(bestp / 96 - ly);
        offout[((size_t)bi * 2 + 1) * LTOT + l] = (float)(bestp % 96 - lx);
    }

    // sparse context accumulation: C[l,n] = 0.25 * sum_c w_c * R[c][n]  (bf16 store)
    float accv[8];
#pragma unroll
    for (int j = 0; j < 8; ++j) accv[j] = 0.f;
    for (int ci = 0; ci < cnt; ++ci) {
        int p = scand[ci];
        float w = __expf(scv[ci] - mx) / Z;
        int F0 = p * 2048 + t;
        int pr = F0 / 2304;
        int s = F0 - pr * 2304;
        int srow = s / 48;
        int scol = s - srow * 48;
#pragma unroll
        for (int j = 0; j < 8; ++j) {
            int ii = pr >> 9, jj = (pr >> 7) & 3, c = pr & 127;
            int Y0 = 2 * srow + ii - 1, X0 = 2 * scol + jj - 1;
            float val = 0.f;
            if (Y0 >= 0 && Y0 < HS && X0 >= 0 && X0 < HS)
                val = bsrc[(((size_t)bi * CS + c) * HS + Y0) * HS + X0];
            accv[j] += w * val;
            scol += 16; if (scol >= 48) { scol -= 48; srow += 1; }
            srow += 5;
            s += 256; if (s >= 2304) { s -= 2304; pr += 1; srow -= 48; }
        }
    }
    u16* Crow = C + (size_t)l * CRED;
#pragma unroll
    for (int j = 0; j < 8; ++j) Crow[t + 256 * j] = f2bf(accv[j] * 0.25f);
}

// ---------------- transposed-conv reduction, LDS-tiled (bf16 C reads) ----------------
__global__ __launch_bounds__(256) void k_output_tiled(const u16* __restrict__ Cg,
                                                      float* __restrict__ yout,
                                                      int b0, size_t zsU) {
    __shared__ float lo[64 * 129];
    int bi = b0 + blockIdx.z;
    const u16* C = Cg + (size_t)blockIdx.z * zsU;
    int bx = blockIdx.x;
    int Y0 = (bx / 6) * 4, X0 = (bx % 6) * 16;
    int t = threadIdx.x;
    int c = t & 127;
    for (int i = 0; i < 32; ++i) {
        int pos = i * 2 + (t >> 7);
        int Y = Y0 + (pos >> 4), X = X0 + (pos & 15);
        float s = 0.f;
        int pu = (Y + 1) & 1, pv = (X + 1) & 1;
#pragma unroll
        for (int a = 0; a < 2; a++) {
            int u = pu + 2 * a;
            int ly2 = Y + 1 - u;
            if (ly2 < 0) continue;
            int ly = ly2 >> 1;
            if (ly >= IH) continue;
#pragma unroll
            for (int bb = 0; bb < 2; bb++) {
                int v = pv + 2 * bb;
                int lx2 = X + 1 - v;
                if (lx2 < 0) continue;
                int lx = lx2 >> 1;
                if (lx >= IW) continue;
                s += bf2f(C[(size_t)(ly * IW + lx) * CRED + u * 512 + v * 128 + c]);
            }
        }
        lo[pos * 129 + c] = s;   // C already carries the 0.25 factor
    }
    __syncthreads();
    for (int i = 0; i < 32; ++i) {
        int cc = i * 4 + (t >> 6);
        int pos = t & 63;
        float val = lo[pos * 129 + cc];
        int yl = pos >> 4, xl = pos & 15;
        yout[(((size_t)bi * CS + cc) * HS + Y0 + yl) * HS + X0 + xl] = val;
    }
}

// ---------------- launch ----------------
extern "C" void kernel_launch(void* const* d_in, const int* in_sizes, int n_in,
                              void* d_out, int out_size, void* d_ws, size_t ws_size,
                              hipStream_t stream) {
    const float* f = (const float*)d_in[0];
    const float* b = (const float*)d_in[1];
    const float* mask = (const float*)d_in[2];
    float* yout = (float*)d_out;
    float* offout = yout + (size_t)4 * CS * HS * HS;

    int ZB, nloop;
    if (ws_size >= 4 * REGION)      { ZB = 4; nloop = 1; }
    else if (ws_size >= 2 * REGION) { ZB = 2; nloop = 2; }
    else                            { ZB = 1; nloop = 4; }

    char* base = (char*)d_ws;
    u16*   Apl  = (u16*)(base + OFF_APL);
    u16*   Bpl  = (u16*)(base + OFF_BPL);
    float* S    = (float*)(base + OFF_S);
    u16*   Cc   = (u16*)(base + OFF_C);
    float* mmv  = (float*)(base + OFF_SM);

    const size_t zsU = REGION / 2;   // per-z stride in u16 elements
    const size_t zsF = REGION / 4;   // per-z stride in float elements

    dim3 blk(256, 1, 1);

    for (int it = 0; it < nloop; ++it) {
        int b0 = it * ZB;
        k_wgather<<<dim3(LTOT, 1, ZB), blk, 0, stream>>>(b, Apl, b0, zsU);
        k_gather_x_tiled<<<dim3(IH * 3, 1, ZB), blk, 0, stream>>>(f, Bpl, b0, zsU);
        k_mm<<<dim3((LTOT + 255) / 256, 1, ZB), blk, 0, stream>>>(mask, mmv, b0, zsF);
        // GEMM1: S[l,p] = Wn . Xp^T : M=N=2304, K=1152, split-2, 3 products, BK=64
        k_gemm_mfma<2, 64><<<dim3(LTOT / 128, LTOT / 128, ZB), blk, 0, stream>>>(
            Apl, Bpl, S, zsU, zsU, zsF, PLANE, LTOT, LTOT, KRED);
        // fused stencil(vectorized)+softmax+argmax + sparse context gather -> C (bf16)
        k_fusesoftmax<<<dim3(LTOT * ZB), blk, 0, stream>>>(S, mmv, b, Cc, offout, b0, zsF, zsU);
        // y via LDS-tiled transpose (bf16 C reads)
        k_output_tiled<<<dim3((HS / 4) * (HS / 16), 1, ZB), blk, 0, stream>>>(Cc, yout, b0, zsU);
    }
}

// Round 20
// 442.130 us; speedup vs baseline: 1.0909x; 1.0909x over previous
//
#include <hip/hip_runtime.h>
#include <hip/hip_bf16.h>
#include <math.h>

#define IH 48
#define IW 48
#define LTOT 2304      // 48*48
#define CS 128
#define HS 96
#define KRED 1152      // 3*3*128
#define CRED 2048      // 4*4*128

typedef unsigned short u16;
typedef __attribute__((ext_vector_type(8))) short short8;
typedef __attribute__((ext_vector_type(8))) unsigned short ushort8;
typedef __attribute__((ext_vector_type(4))) float floatx4;

#define NS    ((size_t)LTOT*LTOT)     // 5,308,416
#define PLANE ((size_t)LTOT*KRED)     // 2,654,208

// ---- region layout (bytes), per batch slice (~52MB; 4x fits ws) ----
#define OFF_APL  ((size_t)0)           // 2 bf16 W planes
#define OFF_BPL  ((size_t)10616832)    // 2 bf16 Xp planes
#define OFF_S    ((size_t)21233664)    // NS fp32 raw scores
#define OFF_C    ((size_t)42467328)    // C rows bf16: 2304*2048*2 B
#define OFF_SM   ((size_t)51904512)    // mmv(2304 f32)
#define REGION   ((size_t)51922944)

__device__ __forceinline__ u16 f2bf(float v) {
    __hip_bfloat16 h = __float2bfloat16(v);
    return *reinterpret_cast<u16*>(&h);
}
__device__ __forceinline__ float bf2f(u16 b) {
    __hip_bfloat16 h = *reinterpret_cast<__hip_bfloat16*>(&b);
    return __bfloat162float(h);
}
__device__ __forceinline__ void split2(float v, u16& a, u16& b) {
    a = f2bf(v);
    b = f2bf(v - bf2f(a));
}

// ---------------- fused W norm + gather + split (register-resident row) ----------------
__global__ __launch_bounds__(256) void k_wgather(const float* __restrict__ b,
                                                 u16* __restrict__ Ag,
                                                 int b0, size_t zsU) {
    int bi = b0 + blockIdx.z;
    u16* A = Ag + (size_t)blockIdx.z * zsU;
    int l = blockIdx.x, t = threadIdx.x;
    __shared__ float red[256];
    float myv[5];
    float ss = 0.f;
#pragma unroll
    for (int k = 0; k < 5; ++k) {
        int G = t + 256 * k;
        float val = 0.f;
        if (G < KRED) {
            int F = l * KRED + G;
            int p2 = F / LTOT, s = F - p2 * LTOT;
            int i = p2 / 384, j = (p2 / 128) % 3, c = p2 & 127;
            int u = s / IW + i - 1, v = s % IW + j - 1;
            if (u >= 0 && u < IH && v >= 0 && v < IW)
                val = b[(((size_t)bi * CS + c) * HS + 2 * u) * HS + 2 * v];
        }
        myv[k] = val;
        ss += val * val;
    }
    red[t] = ss; __syncthreads();
    for (int o = 128; o > 0; o >>= 1) { if (t < o) red[t] += red[t + o]; __syncthreads(); }
    float ninv = 1.0f / fmaxf(sqrtf(red[0] + 1e-8f), 1e-4f);
#pragma unroll
    for (int k = 0; k < 5; ++k) {
        int G = t + 256 * k;
        if (G < KRED) {
            u16 h1, h2; split2(myv[k] * ninv, h1, h2);
            size_t F = (size_t)l * KRED + G;
            A[F] = h1; A[PLANE + F] = h2;
        }
    }
}

// ---------------- gather Xp (split) — LDS-tiled ----------------
__global__ __launch_bounds__(256) void k_gather_x_tiled(const float* __restrict__ f,
                                                        u16* __restrict__ Bg,
                                                        int b0, size_t zsU) {
    __shared__ float ldsf[128 * 55];   // [c][3][18] padded 54->55
    int bi = b0 + blockIdx.z;
    u16* B = Bg + (size_t)blockIdx.z * zsU;
    int bx = blockIdx.x;
    int y = bx / 3, x0 = (bx % 3) * 16;
    int t = threadIdx.x;
    for (int i = 0; i < 27; ++i) {
        int g = i * 256 + t;
        if (g < 6912) {
            int vl = g % 18;
            int row = (g / 18) % 3;
            int c = g / 54;
            int u = y + row - 1;
            int v = x0 - 1 + vl;
            float val = 0.f;
            if (u >= 0 && u < IH && v >= 0 && v < IW)
                val = f[(((size_t)bi * CS + c) * HS + 2 * u) * HS + 2 * v];
            ldsf[c * 55 + row * 18 + vl] = val;
        }
    }
    __syncthreads();
    for (int i = 0; i < 72; ++i) {
        int o = i * 256 + t;
        int xp = o / 1152, G = o - xp * 1152;
        int k1 = G / 384, k2 = (G >> 7) % 3, c = G & 127;
        float val = ldsf[c * 55 + k1 * 18 + xp + k2];
        u16 h1, h2; split2(val, h1, h2);
        size_t idx = (size_t)(y * IW + x0 + xp) * KRED + G;
        B[idx] = h1; B[PLANE + idx] = h2;
    }
}

// ---------------- mask vector ----------------
__global__ __launch_bounds__(256) void k_mm(const float* __restrict__ mask,
                                            float* __restrict__ mmvg, int b0, size_t zsF) {
    int bi = b0 + blockIdx.z;
    float* out = mmvg + (size_t)blockIdx.z * zsF;
    int q = blockIdx.x * 256 + threadIdx.x;
    if (q >= LTOT) return;
    float ssum = 0.f;
    for (int t = 0; t < 9; t++) {
        int F = q * 9 + t;
        int pm = F / LTOT, s = F % LTOT;
        int i = pm / 3, j = pm % 3;
        int u = s / IW + i - 1, v = s % IW + j - 1;
        float val = 0.f;
        if (u >= 0 && u < IH && v >= 0 && v < IW)
            val = mask[((size_t)bi * HS + 2 * u) * HS + 2 * v];
        ssum += 1.0f - val;
    }
    out[q] = (ssum / 9.0f < 0.85f) ? 1.0f : 0.0f;
}

// ---------------- MFMA GEMM (NT) — unchanged proven structure ----------------
template <int NP, int BK>
__global__ __launch_bounds__(256) void k_gemm_mfma(const u16* __restrict__ Ag,
                                                   const u16* __restrict__ Bg,
                                                   float* __restrict__ Cg,
                                                   size_t zsA, size_t zsB, size_t zsC,
                                                   size_t planeStride,
                                                   int M, int N, int K) {
    constexpr int SLOTS = BK / 8;
    constexpr int SMASK = SLOTS - 1;
    constexpr int TSZ = 128 * BK;
    constexpr int NLD = NP * BK / 16;
    __shared__ u16 lds[2 * NP * TSZ];
    u16* As = lds;
    u16* Bs = lds + NP * TSZ;
    const int tid = threadIdx.x;
    const int lane = tid & 63;
    const int wave = tid >> 6;
    const int wr = (wave >> 1) * 64, wc = (wave & 1) * 64;
    const int lrow = lane & 15, lq = lane >> 4;

    unsigned gx = gridDim.x, gy = gridDim.y;
    unsigned nwg = gx * gy * gridDim.z;
    unsigned wg = (blockIdx.z * gy + blockIdx.y) * gx + blockIdx.x;
    {
        unsigned q = nwg >> 3, r = nwg & 7, xcd = wg & 7, lid = wg >> 3;
        wg = (xcd < r ? xcd * (q + 1) : r * (q + 1) + (xcd - r) * q) + lid;
    }
    unsigned z = wg / (gx * gy);
    unsigned rem2 = wg - z * gx * gy;
    const int bm = (int)(rem2 / gx) * 128, bn = (int)(rem2 % gx) * 128;

    const u16* A = Ag + (size_t)z * zsA;
    const u16* B = Bg + (size_t)z * zsB;
    float* C = Cg + (size_t)z * zsC;

    floatx4 acc[4][4];
#pragma unroll
    for (int i = 0; i < 4; i++)
#pragma unroll
        for (int j = 0; j < 4; j++) acc[i][j] = (floatx4){0.f, 0.f, 0.f, 0.f};

    for (int kt = 0; kt < K; kt += BK) {
        ushort8 stA[NLD], stB[NLD];
#pragma unroll
        for (int e = 0; e < NLD; ++e) {
            int g = e * 256 + tid;
            int p = g / (128 * SLOTS);
            int gg = g % (128 * SLOTS);
            int row = gg / SLOTS, slot = gg & SMASK;
            stA[e] = *(const ushort8*)(A + (size_t)p * planeStride + (size_t)(bm + row) * K + kt + slot * 8);
            stB[e] = *(const ushort8*)(B + (size_t)p * planeStride + (size_t)(bn + row) * K + kt + slot * 8);
        }
        __syncthreads();
#pragma unroll
        for (int e = 0; e < NLD; ++e) {
            int g = e * 256 + tid;
            int p = g / (128 * SLOTS);
            int gg = g % (128 * SLOTS);
            int row = gg / SLOTS, slot = gg & SMASK;
            int dst = p * TSZ + row * BK + ((slot ^ (row & SMASK)) << 3);
            *(ushort8*)&As[dst] = stA[e];
            *(ushort8*)&Bs[dst] = stB[e];
        }
        __syncthreads();

#pragma unroll
        for (int ks = 0; ks < BK / 32; ++ks) {
            short8 af[NP][4];
#pragma unroll
            for (int p = 0; p < NP; ++p)
#pragma unroll
                for (int mi = 0; mi < 4; ++mi) {
                    int row = wr + mi * 16 + lrow;
                    af[p][mi] = *(const short8*)&As[p * TSZ + row * BK + ((((ks << 2) | lq) ^ (row & SMASK)) << 3)];
                }
#pragma unroll
            for (int ni = 0; ni < 4; ++ni) {
                short8 bfr[NP];
                int rowb = wc + ni * 16 + lrow;
                int bslot = ((((ks << 2) | lq) ^ (rowb & SMASK)) << 3);
#pragma unroll
                for (int p = 0; p < NP; ++p)
                    bfr[p] = *(const short8*)&Bs[p * TSZ + rowb * BK + bslot];
#pragma unroll
                for (int mi = 0; mi < 4; ++mi) {
                    if constexpr (NP == 1) {
                        acc[mi][ni] = __builtin_amdgcn_mfma_f32_16x16x32_bf16(af[0][mi], bfr[0], acc[mi][ni], 0, 0, 0);
                    } else {
                        acc[mi][ni] = __builtin_amdgcn_mfma_f32_16x16x32_bf16(af[1][mi], bfr[0], acc[mi][ni], 0, 0, 0);
                        acc[mi][ni] = __builtin_amdgcn_mfma_f32_16x16x32_bf16(af[0][mi], bfr[1], acc[mi][ni], 0, 0, 0);
                        acc[mi][ni] = __builtin_amdgcn_mfma_f32_16x16x32_bf16(af[0][mi], bfr[0], acc[mi][ni], 0, 0, 0);
                    }
                }
            }
        }
    }

    const int r0 = bm + wr + (lane >> 4) * 4;
    const int c0 = bn + wc + (lane & 15);
#pragma unroll
    for (int mi = 0; mi < 4; ++mi)
#pragma unroll
        for (int ni = 0; ni < 4; ++ni)
#pragma unroll
            for (int j = 0; j < 4; ++j)
                C[(size_t)(r0 + mi * 16 + j) * N + (c0 + ni * 16)] = acc[mi][ni][j];
}

// ---------------- fused stencil+softmax+argmax + sparse context gather ----------------
// Round-13 passing semantics verbatim; C stored as bf16 (halves C traffic).
__device__ __forceinline__ int permi(int a) { return (a % 48) * 48 + a / 48; }

__global__ __launch_bounds__(256) void k_fusesoftmax(const float* __restrict__ Sg,
                                                     const float* __restrict__ mmg,
                                                     const float* __restrict__ bsrc,
                                                     u16* __restrict__ Cg,
                                                     float* __restrict__ offout,
                                                     int b0, size_t zsF, size_t zsU) {
    // flat bijective XCD swizzle over (z,l): contiguous one-z l-chunk per XCD
    unsigned nwg = gridDim.x;
    unsigned wg0 = blockIdx.x;
    unsigned qq = nwg >> 3, rr = nwg & 7, xcd = wg0 & 7, lid = wg0 >> 3;
    unsigned wg = (xcd < rr ? xcd * (qq + 1) : rr * (qq + 1) + (xcd - rr) * qq) + lid;
    int z = wg / LTOT;
    int l = wg - z * LTOT;
    int bi = b0 + z;
    const float* S = Sg + (size_t)z * zsF;
    const float* mm = mmg + (size_t)z * zsF;
    u16* C = Cg + (size_t)z * zsU;
    int t = threadIdx.x;
    __shared__ float redv[256];
    __shared__ int redi[256];
    __shared__ int scand[2304];
    __shared__ float scv[2304];
    __shared__ int scnt;
    __shared__ int sAny;
    if (t == 0) { scnt = 0; sAny = 0; }

    const bool hasRm = (l >= 1);
    const bool hasRp = (l <= 2302);
    const int rm = hasRm ? ((l >= 48) ? l - 48 : 2255 + l) : 0;
    const int rp = hasRp ? ((l < 2256) ? l + 48 : l - 2255) : 0;
    const float* pr_l  = S + (size_t)l * LTOT;
    const float* pr_lm = S + (size_t)(l >= 1 ? l - 1 : 0) * LTOT;
    const float* pr_lp = S + (size_t)(l < 2303 ? l + 1 : l) * LTOT;
    const float* pr_m  = S + (size_t)rm * LTOT;
    const float* pr_mm = S + (size_t)(rm >= 1 ? rm - 1 : 0) * LTOT;
    const float* pr_mp = S + (size_t)(rm < 2303 ? rm + 1 : rm) * LTOT;
    const float* pr_p  = S + (size_t)rp * LTOT;
    const float* pr_pm = S + (size_t)(rp >= 1 ? rp - 1 : 0) * LTOT;
    const float* pr_pp = S + (size_t)(rp < 2303 ? rp + 1 : rp) * LTOT;
    const bool gLm = (l >= 1), gLp = (l < 2303);
    const bool gMm = (rm >= 1), gMp = (rm < 2303);
    const bool gPm = (rp >= 1), gPp = (rp < 2303);

    float v[9];
    bool mk[9];
    int nMaskLoc = 0;
#pragma unroll
    for (int i = 0; i < 9; ++i) {
        int p = t + 256 * i;
        const bool cm = (p >= 1), cp = (p < 2303);
        int pm = (p >= 48) ? p - 48 : 2255 + p;
        int pp = (p < 2256) ? p + 48 : p - 2255;
        float d = pr_l[p];
        { float x = pr_lm[cm ? p - 1 : 0];            d += (gLm && cm) ? x : 0.f; }
        { float x = pr_lp[cp ? p + 1 : p];            d += (gLp && cp) ? x : 0.f; }
        { float x = pr_m[pm];                         d += (hasRm && cm) ? x : 0.f; }
        { bool g = hasRm && cm && gMm && (pm >= 1);
          float x = pr_mm[(pm >= 1) ? pm - 1 : 0];    d += g ? x : 0.f; }
        { bool g = hasRm && cm && gMp && (pm < 2303);
          float x = pr_mp[(pm < 2303) ? pm + 1 : pm]; d += g ? x : 0.f; }
        { float x = pr_p[pp];                         d += (hasRp && cp) ? x : 0.f; }
        { bool g = hasRp && cp && gPm && (pp >= 1);
          float x = pr_pm[(pp >= 1) ? pp - 1 : 0];    d += g ? x : 0.f; }
        { bool g = hasRp && cp && gPp && (pp < 2303);
          float x = pr_pp[(pp < 2303) ? pp + 1 : pp]; d += g ? x : 0.f; }
        float m = mm[p];
        mk[i] = (m > 0.f);
        if (!mk[i]) nMaskLoc++;
        v[i] = d * m * 10.0f;
    }
    // joint reduction: unmasked max + first index
    float lmu = -1e30f; int lidx = 0x7fffffff;
#pragma unroll
    for (int i = 0; i < 9; ++i) {
        int p = t + 256 * i;
        if (mk[i] && v[i] > lmu) { lmu = v[i]; lidx = p; }
    }
    if (nMaskLoc) sAny = 1;   // benign race
    redv[t] = lmu; redi[t] = lidx; __syncthreads();
    for (int o = 128; o > 0; o >>= 1) {
        if (t < o) {
            if (redv[t + o] > redv[t] || (redv[t + o] == redv[t] && redi[t + o] < redi[t])) {
                redv[t] = redv[t + o]; redi[t] = redi[t + o];
            }
        }
        __syncthreads();
    }
    float mu = redv[0];
    int muIdx = redi[0];
    int anyM = sAny;
    __syncthreads();
    redi[t] = nMaskLoc; __syncthreads();
    for (int o = 128; o > 0; o >>= 1) { if (t < o) redi[t] += redi[t + o]; __syncthreads(); }
    int nMask = redi[0];
    __syncthreads();

    float mx = anyM ? fmaxf(mu, 0.f) : mu;

    // candidates within 20 logits of unmasked max (full list, exact Z)
#pragma unroll
    for (int i = 0; i < 9; ++i) {
        int p = t + 256 * i;
        if (mk[i] && v[i] >= mu - 20.0f) {
            int pos = atomicAdd(&scnt, 1);
            scand[pos] = p;
            scv[pos] = v[i];
        }
    }
    __syncthreads();
    int cnt = scnt;

    float Z = (float)nMask * __expf(0.f - mx);
    for (int ci = 0; ci < cnt; ++ci) Z += __expf(scv[ci] - mx);

    if (t == 0) {
        int bestp = (cnt > 0) ? muIdx : 0;
        int ly = l / IW, lx = l % IW;
        offout[((size_t)bi * 2 + 0) * LTOT + l] = (float)(bestp / 96 - ly);
        offout[((size_t)bi * 2 + 1) * LTOT + l] = (float)(bestp % 96 - lx);
    }

    // sparse context accumulation: C[l,n] = 0.25 * sum_c w_c * R[c][n]  (bf16 store)
    float accv[8];
#pragma unroll
    for (int j = 0; j < 8; ++j) accv[j] = 0.f;
    for (int ci = 0; ci < cnt; ++ci) {
        int p = scand[ci];
        float w = __expf(scv[ci] - mx) / Z;
        int F0 = p * 2048 + t;
        int pr = F0 / 2304;
        int s = F0 - pr * 2304;
        int srow = s / 48;
        int scol = s - srow * 48;
#pragma unroll
        for (int j = 0; j < 8; ++j) {
            int ii = pr >> 9, jj = (pr >> 7) & 3, c = pr & 127;
            int Y0 = 2 * srow + ii - 1, X0 = 2 * scol + jj - 1;
            float val = 0.f;
            if (Y0 >= 0 && Y0 < HS && X0 >= 0 && X0 < HS)
                val = bsrc[(((size_t)bi * CS + c) * HS + Y0) * HS + X0];
            accv[j] += w * val;
            scol += 16; if (scol >= 48) { scol -= 48; srow += 1; }
            srow += 5;
            s += 256; if (s >= 2304) { s -= 2304; pr += 1; srow -= 48; }
        }
    }
    u16* Crow = C + (size_t)l * CRED;
#pragma unroll
    for (int j = 0; j < 8; ++j) Crow[t + 256 * j] = f2bf(accv[j] * 0.25f);
}

// ---------------- transposed-conv reduction, LDS-tiled (bf16 C reads) ----------------
__global__ __launch_bounds__(256) void k_output_tiled(const u16* __restrict__ Cg,
                                                      float* __restrict__ yout,
                                                      int b0, size_t zsU) {
    __shared__ float lo[64 * 129];
    int bi = b0 + blockIdx.z;
    const u16* C = Cg + (size_t)blockIdx.z * zsU;
    int bx = blockIdx.x;
    int Y0 = (bx / 6) * 4, X0 = (bx % 6) * 16;
    int t = threadIdx.x;
    int c = t & 127;
    for (int i = 0; i < 32; ++i) {
        int pos = i * 2 + (t >> 7);
        int Y = Y0 + (pos >> 4), X = X0 + (pos & 15);
        float s = 0.f;
        int pu = (Y + 1) & 1, pv = (X + 1) & 1;
#pragma unroll
        for (int a = 0; a < 2; a++) {
            int u = pu + 2 * a;
            int ly2 = Y + 1 - u;
            if (ly2 < 0) continue;
            int ly = ly2 >> 1;
            if (ly >= IH) continue;
#pragma unroll
            for (int bb = 0; bb < 2; bb++) {
                int v = pv + 2 * bb;
                int lx2 = X + 1 - v;
                if (lx2 < 0) continue;
                int lx = lx2 >> 1;
                if (lx >= IW) continue;
                s += bf2f(C[(size_t)(ly * IW + lx) * CRED + u * 512 + v * 128 + c]);
            }
        }
        lo[pos * 129 + c] = s;   // C already carries the 0.25 factor
    }
    __syncthreads();
    for (int i = 0; i < 32; ++i) {
        int cc = i * 4 + (t >> 6);
        int pos = t & 63;
        float val = lo[pos * 129 + cc];
        int yl = pos >> 4, xl = pos & 15;
        yout[(((size_t)bi * CS + cc) * HS + Y0 + yl) * HS + X0 + xl] = val;
    }
}

// ---------------- launch ----------------
extern "C" void kernel_launch(void* const* d_in, const int* in_sizes, int n_in,
                              void* d_out, int out_size, void* d_ws, size_t ws_size,
                              hipStream_t stream) {
    const float* f = (const float*)d_in[0];
    const float* b = (const float*)d_in[1];
    const float* mask = (const float*)d_in[2];
    float* yout = (float*)d_out;
    float* offout = yout + (size_t)4 * CS * HS * HS;

    int ZB, nloop;
    if (ws_size >= 4 * REGION)      { ZB = 4; nloop = 1; }
    else if (ws_size >= 2 * REGION) { ZB = 2; nloop = 2; }
    else                            { ZB = 1; nloop = 4; }

    char* base = (char*)d_ws;
    u16*   Apl  = (u16*)(base + OFF_APL);
    u16*   Bpl  = (u16*)(base + OFF_BPL);
    float* S    = (float*)(base + OFF_S);
    u16*   Cc   = (u16*)(base + OFF_C);
    float* mmv  = (float*)(base + OFF_SM);

    const size_t zsU = REGION / 2;   // per-z stride in u16 elements
    const size_t zsF = REGION / 4;   // per-z stride in float elements

    dim3 blk(256, 1, 1);

    for (int it = 0; it < nloop; ++it) {
        int b0 = it * ZB;
        k_wgather<<<dim3(LTOT, 1, ZB), blk, 0, stream>>>(b, Apl, b0, zsU);
        k_gather_x_tiled<<<dim3(IH * 3, 1, ZB), blk, 0, stream>>>(f, Bpl, b0, zsU);
        k_mm<<<dim3((LTOT + 255) / 256, 1, ZB), blk, 0, stream>>>(mask, mmv, b0, zsF);
        // GEMM1: S[l,p] = Wn . Xp^T : M=N=2304, K=1152, split-2, 3 products, BK=64
        k_gemm_mfma<2, 64><<<dim3(LTOT / 128, LTOT / 128, ZB), blk, 0, stream>>>(
            Apl, Bpl, S, zsU, zsU, zsF, PLANE, LTOT, LTOT, KRED);
        // fused stencil+softmax+argmax + sparse context gather -> C (bf16)
        k_fusesoftmax<<<dim3(LTOT * ZB), blk, 0, stream>>>(S, mmv, b, Cc, offout, b0, zsF, zsU);
        // y via LDS-tiled transpose (bf16 C reads)
        k_output_tiled<<<dim3((HS / 4) * (HS / 16), 1, ZB), blk, 0, stream>>>(Cc, yout, b0, zsU);
    }
}